// Round 1
// baseline (42.565 us; speedup 1.0000x reference)
//
#include <hip/hip_runtime.h>

// YOLO loss, fp32. pred/target: (B=4096, 14, 14, 30). Output: scalar fp32.
// Memory-bound: 192.7 MB read -> ~31 us roofline at 6.3 TB/s.

#ifndef NBLOCKS
#define NBLOCKS 1024
#endif

__global__ __launch_bounds__(256) void yolo_cells(
    const float* __restrict__ pred, const float* __restrict__ targ,
    float* __restrict__ partial, int ncells)
{
    float acc = 0.0f;
    for (int idx = blockIdx.x * blockDim.x + threadIdx.x; idx < ncells;
         idx += gridDim.x * blockDim.x) {
        const float2* p2 = reinterpret_cast<const float2*>(pred) + (size_t)idx * 15;
        const float2* t2 = reinterpret_cast<const float2*>(targ) + (size_t)idx * 15;
        float p[30], t[30];
#pragma unroll
        for (int i = 0; i < 15; ++i) {
            float2 v = p2[i]; p[2*i] = v.x; p[2*i+1] = v.y;
            float2 u = t2[i]; t[2*i] = u.x; t[2*i+1] = u.y;
        }

        const bool coo = t[4] > 0.0f;
        float cell;
        if (!coo) {
            // background cell: 0.5 * ((p4-t4)^2 + (p9-t9)^2); t[4]==0 here.
            float d4 = p[4] - t[4];
            float d9 = p[9] - t[9];
            cell = 0.5f * (d4 * d4 + d9 * d9);
        } else {
            const float inv14 = 1.0f / 14.0f;
            // xyxy for pred box 0, pred box 1, target box 0 (ref: c=xy/14, half=wh/2)
            float p0x1 = p[0]*inv14 - 0.5f*p[2], p0y1 = p[1]*inv14 - 0.5f*p[3];
            float p0x2 = p[0]*inv14 + 0.5f*p[2], p0y2 = p[1]*inv14 + 0.5f*p[3];
            float p1x1 = p[5]*inv14 - 0.5f*p[7], p1y1 = p[6]*inv14 - 0.5f*p[8];
            float p1x2 = p[5]*inv14 + 0.5f*p[7], p1y2 = p[6]*inv14 + 0.5f*p[8];
            float tx1  = t[0]*inv14 - 0.5f*t[2], ty1  = t[1]*inv14 - 0.5f*t[3];
            float tx2  = t[0]*inv14 + 0.5f*t[2], ty2  = t[1]*inv14 + 0.5f*t[3];

            float at = (tx2 - tx1) * (ty2 - ty1);

            float w0 = fmaxf(fminf(p0x2, tx2) - fmaxf(p0x1, tx1), 0.0f);
            float h0 = fmaxf(fminf(p0y2, ty2) - fmaxf(p0y1, ty1), 0.0f);
            float inter0 = w0 * h0;
            float a0 = (p0x2 - p0x1) * (p0y2 - p0y1);
            float iou0 = inter0 / (a0 + at - inter0);

            float w1 = fmaxf(fminf(p1x2, tx2) - fmaxf(p1x1, tx1), 0.0f);
            float h1 = fmaxf(fminf(p1y2, ty2) - fmaxf(p1y1, ty1), 0.0f);
            float inter1 = w1 * h1;
            float a1 = (p1x2 - p1x1) * (p1y2 - p1y1);
            float iou1 = inter1 / (a1 + at - inter1);

            // jnp.argmax returns FIRST max -> box1 responsible only if strictly greater
            bool  r1      = iou1 > iou0;
            float max_iou = fmaxf(iou0, iou1);

            float prx = r1 ? p[5] : p[0], pry = r1 ? p[6] : p[1];
            float prw = r1 ? p[7] : p[2], prh = r1 ? p[8] : p[3];
            float prc = r1 ? p[9] : p[4];
            float trx = r1 ? t[5] : t[0], try_ = r1 ? t[6] : t[1];
            float trw = r1 ? t[7] : t[2], trh = r1 ? t[8] : t[3];
            float cnr = r1 ? p[4] : p[9];   // not-responsible pred conf

            float dc = prc - max_iou;
            float contain = dc * dc;
            float not_contain = cnr * cnr;

            float dx = prx - trx, dy = pry - try_;
            float dw = sqrtf(prw) - sqrtf(trw);
            float dh = sqrtf(prh) - sqrtf(trh);
            float loc = dx * dx + dy * dy + dw * dw + dh * dh;

            float cls = 0.0f;
#pragma unroll
            for (int k = 10; k < 30; ++k) {
                float d = p[k] - t[k];
                cls += d * d;
            }
            cell = 5.0f * loc + contain + 0.5f * not_contain + cls;
        }
        acc += cell;
    }

    __shared__ float sm[256];
    sm[threadIdx.x] = acc;
    __syncthreads();
#pragma unroll
    for (int s = 128; s > 0; s >>= 1) {
        if (threadIdx.x < s) sm[threadIdx.x] += sm[threadIdx.x + s];
        __syncthreads();
    }
    if (threadIdx.x == 0) partial[blockIdx.x] = sm[0];
}

__global__ __launch_bounds__(256) void yolo_final(
    const float* __restrict__ partial, int n, float* __restrict__ out, float invN)
{
    __shared__ float sm[256];
    float acc = 0.0f;
    for (int i = threadIdx.x; i < n; i += 256) acc += partial[i];
    sm[threadIdx.x] = acc;
    __syncthreads();
#pragma unroll
    for (int s = 128; s > 0; s >>= 1) {
        if (threadIdx.x < s) sm[threadIdx.x] += sm[threadIdx.x + s];
        __syncthreads();
    }
    if (threadIdx.x == 0) out[0] = sm[0] * invN;
}

extern "C" void kernel_launch(void* const* d_in, const int* in_sizes, int n_in,
                              void* d_out, int out_size, void* d_ws, size_t ws_size,
                              hipStream_t stream) {
    const float* pred = (const float*)d_in[0];
    const float* targ = (const float*)d_in[1];
    float* out = (float*)d_out;
    float* partial = (float*)d_ws;   // NBLOCKS floats = 4 KB scratch

    const int ncells = in_sizes[0] / 30;          // B * 14 * 14
    const int B      = ncells / 196;              // batch size N
    const float invN = 1.0f / (float)B;

    yolo_cells<<<NBLOCKS, 256, 0, stream>>>(pred, targ, partial, ncells);
    yolo_final<<<1, 256, 0, stream>>>(partial, NBLOCKS, out, invN);
}

// Round 2
// 38.102 us; speedup vs baseline: 1.1171x; 1.1171x over previous
//
#include <hip/hip_runtime.h>

// YOLO loss, fp32. pred/target: (B=4096, 14, 14, 30). Output: scalar fp32.
// Round 2: pair-of-cells per thread -> float4 loads (4x fewer line requests),
// compiler barrier between loads and compute to force full MLP.

__device__ __forceinline__ float cell_loss(const float* __restrict__ p,
                                           const float* __restrict__ t)
{
    const bool coo = t[4] > 0.0f;
    if (!coo) {
        // background cell: 0.5 * ((p4-t4)^2 + (p9-t9)^2); t[4]==0 here.
        float d4 = p[4] - t[4];
        float d9 = p[9] - t[9];
        return 0.5f * (d4 * d4 + d9 * d9);
    }
    const float inv14 = 1.0f / 14.0f;
    float p0x1 = p[0]*inv14 - 0.5f*p[2], p0y1 = p[1]*inv14 - 0.5f*p[3];
    float p0x2 = p[0]*inv14 + 0.5f*p[2], p0y2 = p[1]*inv14 + 0.5f*p[3];
    float p1x1 = p[5]*inv14 - 0.5f*p[7], p1y1 = p[6]*inv14 - 0.5f*p[8];
    float p1x2 = p[5]*inv14 + 0.5f*p[7], p1y2 = p[6]*inv14 + 0.5f*p[8];
    float tx1  = t[0]*inv14 - 0.5f*t[2], ty1  = t[1]*inv14 - 0.5f*t[3];
    float tx2  = t[0]*inv14 + 0.5f*t[2], ty2  = t[1]*inv14 + 0.5f*t[3];

    float at = (tx2 - tx1) * (ty2 - ty1);

    float w0 = fmaxf(fminf(p0x2, tx2) - fmaxf(p0x1, tx1), 0.0f);
    float h0 = fmaxf(fminf(p0y2, ty2) - fmaxf(p0y1, ty1), 0.0f);
    float inter0 = w0 * h0;
    float a0 = (p0x2 - p0x1) * (p0y2 - p0y1);
    float iou0 = inter0 / (a0 + at - inter0);

    float w1 = fmaxf(fminf(p1x2, tx2) - fmaxf(p1x1, tx1), 0.0f);
    float h1 = fmaxf(fminf(p1y2, ty2) - fmaxf(p1y1, ty1), 0.0f);
    float inter1 = w1 * h1;
    float a1 = (p1x2 - p1x1) * (p1y2 - p1y1);
    float iou1 = inter1 / (a1 + at - inter1);

    // jnp.argmax returns FIRST max -> box1 responsible only if strictly greater
    bool  r1      = iou1 > iou0;
    float max_iou = fmaxf(iou0, iou1);

    float prx = r1 ? p[5] : p[0], pry = r1 ? p[6] : p[1];
    float prw = r1 ? p[7] : p[2], prh = r1 ? p[8] : p[3];
    float prc = r1 ? p[9] : p[4];
    float trx = r1 ? t[5] : t[0], try_ = r1 ? t[6] : t[1];
    float trw = r1 ? t[7] : t[2], trh = r1 ? t[8] : t[3];
    float cnr = r1 ? p[4] : p[9];   // not-responsible pred conf

    float dc = prc - max_iou;
    float contain = dc * dc;
    float not_contain = cnr * cnr;

    float dx = prx - trx, dy = pry - try_;
    float dw = sqrtf(prw) - sqrtf(trw);
    float dh = sqrtf(prh) - sqrtf(trh);
    float loc = dx * dx + dy * dy + dw * dw + dh * dh;

    float cls = 0.0f;
#pragma unroll
    for (int k = 10; k < 30; ++k) {
        float d = p[k] - t[k];
        cls += d * d;
    }
    return 5.0f * loc + contain + 0.5f * not_contain + cls;
}

__global__ __launch_bounds__(256) void yolo_cells(
    const float* __restrict__ pred, const float* __restrict__ targ,
    float* __restrict__ partial, int npairs)
{
    float acc = 0.0f;
    const int pair = blockIdx.x * 256 + threadIdx.x;
    if (pair < npairs) {
        float p[60], t[60];
        const float4* P4 = reinterpret_cast<const float4*>(pred) + (size_t)pair * 15;
        const float4* T4 = reinterpret_cast<const float4*>(targ) + (size_t)pair * 15;
#pragma unroll
        for (int i = 0; i < 15; ++i) {
            float4 v = P4[i];
            p[4*i+0] = v.x; p[4*i+1] = v.y; p[4*i+2] = v.z; p[4*i+3] = v.w;
        }
#pragma unroll
        for (int i = 0; i < 15; ++i) {
            float4 v = T4[i];
            t[4*i+0] = v.x; t[4*i+1] = v.y; t[4*i+2] = v.z; t[4*i+3] = v.w;
        }
        // Keep all 30 loads issued before any compute: force MLP.
        asm volatile("" ::: "memory");

        acc  = cell_loss(p,      t);
        acc += cell_loss(p + 30, t + 30);
    }

    __shared__ float sm[256];
    sm[threadIdx.x] = acc;
    __syncthreads();
#pragma unroll
    for (int s = 128; s > 0; s >>= 1) {
        if (threadIdx.x < s) sm[threadIdx.x] += sm[threadIdx.x + s];
        __syncthreads();
    }
    if (threadIdx.x == 0) partial[blockIdx.x] = sm[0];
}

__global__ __launch_bounds__(256) void yolo_final(
    const float* __restrict__ partial, int n, float* __restrict__ out, float invN)
{
    __shared__ float sm[256];
    float acc = 0.0f;
    for (int i = threadIdx.x; i < n; i += 256) acc += partial[i];
    sm[threadIdx.x] = acc;
    __syncthreads();
#pragma unroll
    for (int s = 128; s > 0; s >>= 1) {
        if (threadIdx.x < s) sm[threadIdx.x] += sm[threadIdx.x + s];
        __syncthreads();
    }
    if (threadIdx.x == 0) out[0] = sm[0] * invN;
}

extern "C" void kernel_launch(void* const* d_in, const int* in_sizes, int n_in,
                              void* d_out, int out_size, void* d_ws, size_t ws_size,
                              hipStream_t stream) {
    const float* pred = (const float*)d_in[0];
    const float* targ = (const float*)d_in[1];
    float* out = (float*)d_out;
    float* partial = (float*)d_ws;

    const int ncells = in_sizes[0] / 30;          // B * 14 * 14 (even)
    const int B      = ncells / 196;              // batch size N
    const float invN = 1.0f / (float)B;

    const int npairs = ncells / 2;                // 240 B per pair, float4-aligned
    const int nblocks = (npairs + 255) / 256;     // 1568 for B=4096

    yolo_cells<<<nblocks, 256, 0, stream>>>(pred, targ, partial, npairs);
    yolo_final<<<1, 256, 0, stream>>>(partial, nblocks, out, invN);
}